// Round 21
// baseline (110.244 us; speedup 1.0000x reference)
//
#include <hip/hip_runtime.h>
#include <hip/hip_bf16.h>

#define NEX 4096
#define M   256
#define NM  (NEX*M)

typedef __attribute__((ext_vector_type(8))) short short8;
typedef __attribute__((ext_vector_type(4))) float floatx4;
typedef __attribute__((ext_vector_type(16))) float floatx16;
typedef __attribute__((ext_vector_type(4))) unsigned short ushort4v;

__device__ inline unsigned short f2bfu(float x) {
    __hip_bfloat16 h = __float2bfloat16(x);
    union { __hip_bfloat16 b; unsigned short u; } cv; cv.b = h;
    return cv.u;
}
__device__ inline float bfu2f(unsigned short u) {
    union { unsigned short u; __hip_bfloat16 b; } cv; cv.u = u;
    return __bfloat162float(cv.b);
}

// ---------------- fused prep kernel ----------------
// 32x32x16 frag order (k_heavy): lane&31 = row/col, k = ks*16 + (lane>>5)*8 + e.
// 16x16x32 frag order (k_fb): lane&15 = row/col, k = ks*32 + (lane>>4)*8 + e.
__global__ void k_prep(const float* __restrict__ Wd, const float* __restrict__ W0,
                       const float* __restrict__ A,
                       unsigned short* __restrict__ FB32,
                       unsigned short* __restrict__ FB16,
                       unsigned short* __restrict__ FBT16,
                       unsigned short* __restrict__ FW016,
                       unsigned short* __restrict__ FWT16,
                       unsigned short* __restrict__ FSA16,
                       float* __restrict__ FA,
                       float* __restrict__ ksq, float* __restrict__ trace) {
    int b = blockIdx.x, t = threadIdx.x;
    int lane = t & 63, l31 = lane & 31, lhi = lane >> 5;
    int l15 = lane & 15, lg4 = lane >> 4;
    if (b < 64) {
        int combo = b*4 + (t >> 6);
        int l = combo >> 7, rest = combo & 127;
        int mtile = rest >> 4, kstep = rest & 15;
        const float* src = Wd + l*65536 + (mtile*32 + l31)*256 + kstep*16 + lhi*8;
        int off = l*65536 + (mtile*16 + kstep)*512 + lane*8;
        #pragma unroll
        for (int e = 0; e < 8; ++e) FB32[off+e] = f2bfu(src[e]);
    } else if (b < 128) {
        int combo = (b-64)*4 + (t >> 6);
        int l = combo >> 7, rest = combo & 127;
        int mt = rest >> 3, ks = rest & 7;
        const float* src = Wd + l*65536 + (mt*16 + l15)*256 + ks*32 + lg4*8;
        int off = l*65536 + (mt*8 + ks)*512 + lane*8;
        #pragma unroll
        for (int e = 0; e < 8; ++e) FB16[off+e] = f2bfu(src[e]);
    } else if (b < 192) {
        int combo = (b-128)*4 + (t >> 6);
        int l = combo >> 7, rest = combo & 127;
        int kt = rest >> 3, ms = rest & 7;
        const float* src = Wd + l*65536 + (ms*32 + lg4*8)*256 + kt*16 + l15;
        int off = l*65536 + (kt*8 + ms)*512 + lane*8;
        #pragma unroll
        for (int e = 0; e < 8; ++e) FBT16[off+e] = f2bfu(src[e*256]);
    } else if (b < 200) {
        int combo = (b-192)*4 + (t >> 6);
        int mt = combo >> 1, ks = combo & 1;
        const float* src = W0 + (mt*16 + l15)*64 + ks*32 + lg4*8;
        int off = combo*512 + lane*8;
        #pragma unroll
        for (int e = 0; e < 8; ++e) FW016[off+e] = f2bfu(src[e]);
    } else if (b < 208) {
        int combo = (b-200)*4 + (t >> 6);
        int ct = combo >> 3, ms = combo & 7;
        const float* src = W0 + (ms*32 + lg4*8)*64 + ct*16 + l15;
        int off = combo*512 + lane*8;
        #pragma unroll
        for (int e = 0; e < 8; ++e) FWT16[off+e] = f2bfu(src[e*64]);
    } else if (b < 210) {
        int combo = (b-208)*4 + (t >> 6);
        int ct = combo >> 1, ks = combo & 1;
        int c = ct*16 + l15;
        int off = combo*512 + lane*8;
        #pragma unroll
        for (int e = 0; e < 8; ++e) {
            int j = ks*32 + lg4*8 + e;
            float s = 0.f;
            #pragma unroll
            for (int r = 0; r < 10; ++r) s += A[r*64+c] * A[r*64+j];
            FSA16[off+e] = f2bfu(s);
        }
    } else if (b == 210) {
        float s = 0.f;
        for (int dd = 0; dd < 63; dd++) { float v = W0[t*64+dd]; s += v*v; }
        ksq[t] = s;
        float p = 0.f;
        for (int idx = t; idx < 630; idx += 256) {
            int r = idx / 63, i = idx % 63;
            float v = A[r*64+i]; p += v*v;
        }
        for (int off = 32; off; off >>= 1) p += __shfl_down(p, off, 64);
        __shared__ float red[4];
        if ((t & 63) == 0) red[t >> 6] = p;
        __syncthreads();
        if (t == 0) trace[0] = red[0]+red[1]+red[2]+red[3];
    } else {
        int q = (b-211)*256 + t;            // [0,2048)
        int tl = q & 63, frag = q >> 6;     // frag = dh*16+ks in [0,32)
        int d  = (frag >> 4)*32 + (tl & 31);
        int m0 = (frag & 15)*16 + (tl >> 5)*8;
        float* dst = FA + q*8;
        #pragma unroll
        for (int e = 0; e < 8; ++e)
            dst[e] = (d == 63) ? 0.f : W0[(m0 + e)*64 + d];
    }
}

// ---------------- fused fwd+bwd MFMA kernel: 16 ex/block, 256 blocks, 512 thr ----------------
__global__ __launch_bounds__(512, 1) void k_fb(
        const float* __restrict__ x, const float* __restrict__ b0,
        const float* __restrict__ bd, const float* __restrict__ wv,
        const float* __restrict__ cw,
        const unsigned short* __restrict__ FW016,
        const unsigned short* __restrict__ FB16,
        const unsigned short* __restrict__ FBT16,
        const unsigned short* __restrict__ FWT16,
        const unsigned short* __restrict__ FSA16,
        float* __restrict__ tanhopen, float* __restrict__ tp0g,
        float* __restrict__ tp1g, float* __restrict__ z2T, float* __restrict__ z1T,
        float* __restrict__ out) {
    __shared__ __align__(16) unsigned short Buh[4096], Bul[4096];   // 8 ks x 512
    __shared__ __align__(16) unsigned short Bxh[1024], Bxl[1024];   // 2 ks x 512
    __shared__ __align__(16) float bounce[16*257];                  // also gpart[8*256]
    __shared__ float b0s[256], bd0s[256], bd1s[256], wvs[256], cws[64];
    int n0 = blockIdx.x * 16, t = threadIdx.x;
    int lane = t & 63, w = t >> 6, l15 = lane & 15, lg4 = lane >> 4;

    if (t < 256) { b0s[t]=b0[t]; bd0s[t]=bd[t]; bd1s[t]=bd[256+t]; wvs[t]=wv[t]; }
    if (t >= 256 && t < 320) cws[t-256] = cw[t-256];
    if (t < 128) {
        int tl = t & 63;
        int ex = tl & 15, k0 = (t >> 6)*32 + (tl >> 4)*8;
        const float* xp = x + (n0+ex)*64 + k0;
        short8 h8, l8;
        #pragma unroll
        for (int e = 0; e < 8; ++e) {
            float v = xp[e];
            unsigned short h = f2bfu(v);
            h8[e] = (short)h; l8[e] = (short)f2bfu(v - bfu2f(h));
        }
        *reinterpret_cast<short8*>(&Bxh[t*8]) = h8;
        *reinterpret_cast<short8*>(&Bxl[t*8]) = l8;
    }
    __syncthreads();

#define MROW(J, R) ((w*2+(J))*16 + lg4*4 + (R))

#define GEMM256_16(PH) do { \
    _Pragma("unroll") \
    for (int ks = 0; ks < 8; ++ks) { \
        short8 Bh = *reinterpret_cast<const short8*>(&Buh[(ks*64+lane)*8]); \
        short8 Bl = *reinterpret_cast<const short8*>(&Bul[(ks*64+lane)*8]); \
        _Pragma("unroll") \
        for (int j = 0; j < 2; ++j) { \
            short8 Aj = *reinterpret_cast<const short8*>(PH + ((w*2+j)*8 + ks)*512 + lane*8); \
            acc[j] = __builtin_amdgcn_mfma_f32_16x16x32_bf16(Aj, Bh, acc[j], 0, 0, 0); \
            acc[j] = __builtin_amdgcn_mfma_f32_16x16x32_bf16(Aj, Bl, acc[j], 0, 0, 0); \
        } \
    } \
} while (0)

#define EPILOGUE(SVAL, DST, BVAL) do { \
    __syncthreads(); \
    _Pragma("unroll") \
    for (int v = 0; v < 8; ++v) bounce[l15*257 + MROW(v>>2, v&3)] = SVAL[v]; \
    _Pragma("unroll") \
    for (int j = 0; j < 2; ++j) { \
        int m0_ = (w*2+j)*16 + lg4*4; \
        int base_ = (((m0_>>5)*64) + ((m0_>>3)&3)*16 + l15)*8 + (m0_&7); \
        ushort4v h4, l4; \
        _Pragma("unroll") \
        for (int q = 0; q < 4; ++q) { \
            float v_ = BVAL[j*4+q]; \
            unsigned short h_ = f2bfu(v_); \
            h4[q] = h_; l4[q] = f2bfu(v_ - bfu2f(h_)); \
        } \
        *reinterpret_cast<ushort4v*>(&Buh[base_]) = h4; \
        *reinterpret_cast<ushort4v*>(&Bul[base_]) = l4; \
    } \
    __syncthreads(); \
    _Pragma("unroll") \
    for (int i = 0; i < 8; ++i) { \
        int f = t + i*512; int ex_ = f >> 8, m_ = f & 255; \
        DST[(n0+ex_)*256 + m_] = bounce[ex_*257 + m_]; \
    } \
} while (0)

    floatx4 acc[2];
    float sv[8], u0v[8], tp0v[8], z2v[8], cf[8];

    // ---- opening (K=64, A=FW016, B=Bx) ----
    #pragma unroll
    for (int j = 0; j < 2; ++j) acc[j] = (floatx4){0.f,0.f,0.f,0.f};
    #pragma unroll
    for (int ks = 0; ks < 2; ++ks) {
        short8 Bh = *reinterpret_cast<const short8*>(&Bxh[(ks*64+lane)*8]);
        short8 Bl = *reinterpret_cast<const short8*>(&Bxl[(ks*64+lane)*8]);
        #pragma unroll
        for (int j = 0; j < 2; ++j) {
            short8 Aj = *reinterpret_cast<const short8*>(FW016 + ((w*2+j)*2 + ks)*512 + lane*8);
            acc[j] = __builtin_amdgcn_mfma_f32_16x16x32_bf16(Aj, Bh, acc[j], 0, 0, 0);
            acc[j] = __builtin_amdgcn_mfma_f32_16x16x32_bf16(Aj, Bl, acc[j], 0, 0, 0);
        }
    }
    #pragma unroll
    for (int v = 0; v < 8; ++v) {
        float p = acc[v>>2][v&3] + b0s[MROW(v>>2, v&3)];
        float a = fabsf(p);
        float e = __expf(-2.f*a);
        float th = (1.f - e) * __builtin_amdgcn_rcpf(1.f + e);
        sv[v] = __builtin_copysignf(th, p);
        u0v[v] = a + __logf(1.f + e);
    }
    EPILOGUE(sv, tanhopen, u0v);

    // ---- pre0 (A=FB16 layer0, B=u0) ----
    #pragma unroll
    for (int j = 0; j < 2; ++j) acc[j] = (floatx4){0.f,0.f,0.f,0.f};
    GEMM256_16(FB16);
    #pragma unroll
    for (int v = 0; v < 8; ++v) {
        float p = acc[v>>2][v&3] + bd0s[MROW(v>>2, v&3)];
        float a = fabsf(p);
        float e = __expf(-2.f*a);
        float th = (1.f - e) * __builtin_amdgcn_rcpf(1.f + e);
        tp0v[v] = __builtin_copysignf(th, p);
        u0v[v] += 0.5f*(a + __logf(1.f + e));   // now u1
    }
    EPILOGUE(tp0v, tp0g, u0v);

    // ---- pre1 (A=FB16 layer1, B=u1) ----
    #pragma unroll
    for (int j = 0; j < 2; ++j) acc[j] = (floatx4){0.f,0.f,0.f,0.f};
    GEMM256_16(FB16 + 65536);
    #pragma unroll
    for (int v = 0; v < 8; ++v) {
        float p = acc[v>>2][v&3] + bd1s[MROW(v>>2, v&3)];
        float a = fabsf(p);
        float e = __expf(-2.f*a);
        float th = (1.f - e) * __builtin_amdgcn_rcpf(1.f + e);
        cf[v] = __builtin_copysignf(th, p);
        z2v[v] = cf[v] * wvs[MROW(v>>2, v&3)];   // coef2 = tp1*wv
    }
    EPILOGUE(cf, tp1g, z2v);

    // ---- z2 (A=FBT16 layer1, B=coef2) ----
    #pragma unroll
    for (int j = 0; j < 2; ++j) acc[j] = (floatx4){0.f,0.f,0.f,0.f};
    GEMM256_16(FBT16 + 65536);
    #pragma unroll
    for (int v = 0; v < 8; ++v) {
        z2v[v] = wvs[MROW(v>>2, v&3)] + 0.5f*acc[v>>2][v&3];
        cf[v] = tp0v[v] * z2v[v];                // coef1
    }
    EPILOGUE(z2v, z2T, cf);

    // ---- z1 (A=FBT16 layer0, B=coef1) ----
    #pragma unroll
    for (int j = 0; j < 2; ++j) acc[j] = (floatx4){0.f,0.f,0.f,0.f};
    GEMM256_16(FBT16);
    #pragma unroll
    for (int v = 0; v < 8; ++v) {
        z2v[v] += 0.5f*acc[v>>2][v&3];           // now z1
        cf[v] = sv[v] * z2v[v];                  // coef0
    }
    EPILOGUE(z2v, z1T, cf);

    // ---- grad: c-tile ct = w&3, K-seg = w>>2; A=FWT16 (coef0) + FSA16 (x, seg1) ----
    {
        int ct = w & 3, seg = w >> 2;
        floatx4 ga = (floatx4){0.f,0.f,0.f,0.f};
        #pragma unroll
        for (int k2 = 0; k2 < 4; ++k2) {
            int ms = seg*4 + k2;
            short8 Bh = *reinterpret_cast<const short8*>(&Buh[(ms*64+lane)*8]);
            short8 Bl = *reinterpret_cast<const short8*>(&Bul[(ms*64+lane)*8]);
            short8 Aj = *reinterpret_cast<const short8*>(FWT16 + (ct*8 + ms)*512 + lane*8);
            ga = __builtin_amdgcn_mfma_f32_16x16x32_bf16(Aj, Bh, ga, 0, 0, 0);
            ga = __builtin_amdgcn_mfma_f32_16x16x32_bf16(Aj, Bl, ga, 0, 0, 0);
        }
        if (seg == 1) {
            #pragma unroll
            for (int ks = 0; ks < 2; ++ks) {
                short8 Bh = *reinterpret_cast<const short8*>(&Bxh[(ks*64+lane)*8]);
                short8 Bl = *reinterpret_cast<const short8*>(&Bxl[(ks*64+lane)*8]);
                short8 Aj = *reinterpret_cast<const short8*>(FSA16 + (ct*2 + ks)*512 + lane*8);
                ga = __builtin_amdgcn_mfma_f32_16x16x32_bf16(Aj, Bh, ga, 0, 0, 0);
                ga = __builtin_amdgcn_mfma_f32_16x16x32_bf16(Aj, Bl, ga, 0, 0, 0);
            }
        }
        __syncthreads();   // bounce free (z1 stores done)
        float* gpart = bounce;   // [8 w][16 row][16 ex]
        #pragma unroll
        for (int r = 0; r < 4; ++r) gpart[w*256 + (lg4*4 + r)*16 + l15] = ga[r];
        __syncthreads();
        if (t < 256) {
            int o0 = t*4, ex = o0 >> 6, c0 = o0 & 63;
            float4 gv;
            #pragma unroll
            for (int jj = 0; jj < 4; ++jj) {
                int c = c0 + jj;
                int ct2 = c >> 4, cr = c & 15;
                gv[jj] = cws[c] + gpart[ct2*256 + cr*16 + ex]
                                + gpart[(ct2+4)*256 + cr*16 + ex];
            }
            *reinterpret_cast<float4*>(&out[(n0+ex)*64 + c0]) = gv;
        }
    }
#undef MROW
#undef GEMM256_16
#undef EPILOGUE
}

// ---------------- heavy Jacobian kernel: lgkm-only barriers, global-fed build ----------------
// Round-20 structure with: (1) Bf build reads tanhopen from global/L2 (barrier 1
// removed, ss[] deleted); (2) mid-kernel barriers wait lgkmcnt(0) ONLY via raw
// s_barrier — global A-prefetches (vmcnt) stay in flight across the RMW barrier.
// All cross-wave hazards are LDS (Bf, tp0s/w1s/w2s), so lgkm ordering suffices.
__global__ __launch_bounds__(256, 4) void k_heavy_mfma(
        const float* __restrict__ tanhopen, const float* __restrict__ tp0,
        const float* __restrict__ tp1, const float* __restrict__ z2T,
        const float* __restrict__ z1T, const float* __restrict__ wv,
        const float* __restrict__ FA, const unsigned short* __restrict__ FB,
        const float* __restrict__ ksq, const float* __restrict__ trace,
        float* __restrict__ outTrH) {
    __shared__ __align__(16) unsigned short Bf[16384];   // 32 KB: 32 frags x 512
    __shared__ float tp0s[256], w1s[256], w2s[256];
    __shared__ float red[4];
    int n = blockIdx.x, t = threadIdx.x;           // t in [0,256)
    int lane = t & 63, w = t >> 6, l31 = lane & 31, lhi = lane >> 5;

#define LBAR() do { \
    asm volatile("s_waitcnt lgkmcnt(0)" ::: "memory"); \
    __builtin_amdgcn_s_barrier(); \
    __builtin_amdgcn_sched_barrier(0); \
} while (0)

    float sv = tanhopen[n*256 + t];
    float a0 = tp0[n*256 + t];
    float a1 = tp1[n*256 + t];
    tp0s[t] = a0;
    w1s[t] = (1.f - a0*a0) * z2T[n*256 + t];
    w2s[t] = (1.f - a1*a1) * wv[t];
    float tot = (1.f - sv*sv) * z1T[n*256 + t] * ksq[t];   // trH layer-0 partial (m=t)

    // build Bf[frag= dh*16+ks][tl][e] = bf16( W0T[d][k] * s[k] ) — s from GLOBAL
    #pragma unroll
    for (int i = 0; i < 8; ++i) {
        int q = t + i*256;                  // [0,2048) lane-chunks of short8
        int frag = q >> 6, tl = q & 63;
        int k0 = (frag & 15)*16 + (tl >> 5)*8;
        const float* fp = FA + q*8;         // FA layout matches frag*64+tl
        const float* sp = tanhopen + n*256 + k0;
        short8 v8;
        #pragma unroll
        for (int e = 0; e < 8; ++e)
            v8[e] = (short)f2bfu(fp[e] * sp[e]);
        *reinterpret_cast<short8*>(&Bf[q*8]) = v8;
    }
    LBAR();   // stats + Bf ds_writes visible; no vmcnt drain

    floatx16 acc[2][2];   // [m-tile jm][d-half dh]
    int mt0 = w*2, mt1 = w*2 + 1;
    float wtot = 0.f;

    const unsigned short* pA0 = FB + mt0*16*512 + lane*8;   // layer 0, ks stride 512
    const unsigned short* pA1 = FB + mt1*16*512 + lane*8;
    const unsigned short* qB0 = &Bf[lane*8];                // dh=0, ks stride 512
    const unsigned short* qB1 = &Bf[(16*64 + lane)*8];      // dh=1

#define LD8(P, KS) (*reinterpret_cast<const short8*>((P) + (KS)*512))
#define MFMA4(A0_, A1_, B0_, B1_) do { \
    acc[0][0] = __builtin_amdgcn_mfma_f32_32x32x16_bf16(A0_, B0_, acc[0][0], 0, 0, 0); \
    acc[0][1] = __builtin_amdgcn_mfma_f32_32x32x16_bf16(A0_, B1_, acc[0][1], 0, 0, 0); \
    acc[1][0] = __builtin_amdgcn_mfma_f32_32x32x16_bf16(A1_, B0_, acc[1][0], 0, 0, 0); \
    acc[1][1] = __builtin_amdgcn_mfma_f32_32x32x16_bf16(A1_, B1_, acc[1][1], 0, 0, 0); \
} while (0)

    // ---------------- layer 0: KJ1 = Wd0 @ Jac (4-deep A, 2-deep B) ----------------
    #pragma unroll
    for (int jm = 0; jm < 2; ++jm)
        #pragma unroll
        for (int dh = 0; dh < 2; ++dh)
            #pragma unroll
            for (int r = 0; r < 16; ++r) acc[jm][dh][r] = 0.f;

    __builtin_amdgcn_s_setprio(1);
    {
        short8 A0s[4], A1s[4], B0s[2], B1s[2];
        A0s[0] = LD8(pA0, 0); A1s[0] = LD8(pA1, 0);
        A0s[1] = LD8(pA0, 1); A1s[1] = LD8(pA1, 1);
        A0s[2] = LD8(pA0, 2); A1s[2] = LD8(pA1, 2);
        B0s[0] = LD8(qB0, 0); B1s[0] = LD8(qB1, 0);
        #pragma unroll
        for (int ks = 0; ks < 16; ++ks) {
            if (ks + 3 < 16) {
                A0s[(ks+3)&3] = LD8(pA0, ks+3);
                A1s[(ks+3)&3] = LD8(pA1, ks+3);
            }
            if (ks + 1 < 16) {
                B0s[(ks+1)&1] = LD8(qB0, ks+1);
                B1s[(ks+1)&1] = LD8(qB1, ks+1);
            }
            MFMA4(A0s[ks&3], A1s[ks&3], B0s[ks&1], B1s[ks&1]);
        }
    }
    __builtin_amdgcn_s_setprio(0);

    // prefetch layer-1 first A stages (global; stays in flight across LBAR)
    const unsigned short* pC0 = FB + 65536 + mt0*16*512 + lane*8;
    const unsigned short* pC1 = FB + 65536 + mt1*16*512 + lane*8;
    short8 nA00 = LD8(pC0, 0), nA10 = LD8(pC1, 0);
    short8 nA01 = LD8(pC0, 1), nA11 = LD8(pC1, 1);
    short8 nA02 = LD8(pC0, 2), nA12 = LD8(pC1, 2);

    LBAR();   // all layer-0 B ds_reads done before update writes (vmcnt NOT drained)

    // trH layer-1 + Jac update: Jac[m][d] += 0.5*tp0[m]*KJ1[m][d]
    #pragma unroll
    for (int jm = 0; jm < 2; ++jm) {
        int mt = w*2 + jm;
        #pragma unroll
        for (int g = 0; g < 4; ++g) {
            float w1m[4], tm[4];
            #pragma unroll
            for (int q = 0; q < 4; ++q) {
                int m = mt*32 + 8*g + q + 4*lhi;
                w1m[q] = 0.5f * w1s[m];
                tm[q]  = 0.5f * tp0s[m];
            }
            #pragma unroll
            for (int dh = 0; dh < 2; ++dh) {
                int base = ((dh*16 + mt*2 + (g >> 1))*64
                            + ((g & 1)*32 + l31))*8 + 4*lhi;
                ushort4v old = *reinterpret_cast<ushort4v*>(&Bf[base]);
                ushort4v nw;
                #pragma unroll
                for (int q = 0; q < 4; ++q) {
                    float v = acc[jm][dh][4*g + q];
                    wtot += w1m[q] * v * v;
                    nw[q] = f2bfu(bfu2f(old[q]) + tm[q] * v);
                }
                *reinterpret_cast<ushort4v*>(&Bf[base]) = nw;
            }
        }
    }
    LBAR();   // updates visible before layer-1 reads

    // ---------------- layer 1: KJ2 = Wd1 @ Jac_new (4-deep A, 2-deep B) ----------------
    #pragma unroll
    for (int jm = 0; jm < 2; ++jm)
        #pragma unroll
        for (int dh = 0; dh < 2; ++dh)
            #pragma unroll
            for (int r = 0; r < 16; ++r) acc[jm][dh][r] = 0.f;

    __builtin_amdgcn_s_setprio(1);
    {
        short8 A0s[4], A1s[4], B0s[2], B1s[2];
        A0s[0] = nA00; A1s[0] = nA10;
        A0s[1] = nA01; A1s[1] = nA11;
        A0s[2] = nA02; A1s[2] = nA12;
        B0s[0] = LD8(qB0, 0); B1s[0] = LD8(qB1, 0);
        #pragma unroll
        for (int ks = 0; ks < 16; ++ks) {
            if (ks + 3 < 16) {
                A0s[(ks+3)&3] = LD8(pC0, ks+3);
                A1s[(ks+3)&3] = LD8(pC1, ks+3);
            }
            if (ks + 1 < 16) {
                B0s[(ks+1)&1] = LD8(qB0, ks+1);
                B1s[(ks+1)&1] = LD8(qB1, ks+1);
            }
            MFMA4(A0s[ks&3], A1s[ks&3], B0s[ks&1], B1s[ks&1]);
        }
    }
    __builtin_amdgcn_s_setprio(0);
#undef MFMA4
#undef LD8

    // trH layer-2 term
    #pragma unroll
    for (int jm = 0; jm < 2; ++jm)
        #pragma unroll
        for (int g = 0; g < 4; ++g)
            #pragma unroll
            for (int q = 0; q < 4; ++q) {
                int m = (w*2 + jm)*32 + 8*g + q + 4*lhi;
                float w2m = 0.5f * w2s[m];
                float v0 = acc[jm][0][4*g + q], v1 = acc[jm][1][4*g + q];
                wtot += w2m * (v0*v0 + v1*v1);
            }

    tot += wtot;

    // reduce 256 -> 1
    for (int off = 32; off; off >>= 1) tot += __shfl_down(tot, off, 64);
    if (lane == 0) red[w] = tot;
    __syncthreads();
    if (t == 0) outTrH[n] = red[0] + red[1] + red[2] + red[3] + trace[0];
#undef LBAR
}

// ---------------- launcher ----------------

extern "C" void kernel_launch(void* const* d_in, const int* in_sizes, int n_in,
                              void* d_out, int out_size, void* d_ws, size_t ws_size,
                              hipStream_t stream) {
    const float* x   = (const float*)d_in[0];   // 4096*64
    const float* W0  = (const float*)d_in[1];   // 256*64
    const float* b0  = (const float*)d_in[2];   // 256
    const float* Wd  = (const float*)d_in[3];   // 2*256*256
    const float* bd  = (const float*)d_in[4];   // 2*256
    const float* wv  = (const float*)d_in[5];   // 256
    const float* A   = (const float*)d_in[6];   // 10*64
    const float* cw  = (const float*)d_in[7];   // 64
    float* out = (float*)d_out;
    float* ws  = (float*)d_ws;

    float* tanhopen = ws;               // NM
    float* tp0  = tanhopen + NM;        // NM
    float* tp1  = tp0 + NM;             // NM
    float* z2T  = tp1 + NM;             // NM
    float* z1T  = z2T + NM;             // NM
    float* FA   = z1T + NM;             // 16384
    float* ksq  = FA + 16384;           // 256
    float* trace= ksq + 256;            // 4 (padded for alignment)
    unsigned short* FB32  = (unsigned short*)(trace + 4); // 131072
    unsigned short* FB16  = FB32 + 131072;                // 131072
    unsigned short* FBT16 = FB16 + 131072;                // 131072
    unsigned short* FW016 = FBT16 + 131072;               // 16384
    unsigned short* FWT16 = FW016 + 16384;                // 16384
    unsigned short* FSA16 = FWT16 + 16384;                // 4096

    k_prep<<<219, 256, 0, stream>>>(Wd, W0, A, FB32, FB16, FBT16,
                                    FW016, FWT16, FSA16, FA, ksq, trace);
    k_fb<<<NEX/16, 512, 0, stream>>>(x, b0, bd, wv, cw,
                                     FW016, FB16, FBT16, FWT16, FSA16,
                                     tanhopen, tp0, tp1, z2T, z1T, out);
    k_heavy_mfma<<<NEX, 256, 0, stream>>>(tanhopen, tp0, tp1, z2T, z1T, wv,
                                          FA, FB32, ksq, trace, out + NEX*64);
}

// Round 22
// 104.990 us; speedup vs baseline: 1.0500x; 1.0500x over previous
//
#include <hip/hip_runtime.h>
#include <hip/hip_bf16.h>

#define NEX 4096
#define M   256
#define NM  (NEX*M)

typedef __attribute__((ext_vector_type(8))) short short8;
typedef __attribute__((ext_vector_type(4))) float floatx4;
typedef __attribute__((ext_vector_type(16))) float floatx16;
typedef __attribute__((ext_vector_type(4))) unsigned short ushort4v;

__device__ inline unsigned short f2bfu(float x) {
    __hip_bfloat16 h = __float2bfloat16(x);
    union { __hip_bfloat16 b; unsigned short u; } cv; cv.b = h;
    return cv.u;
}
__device__ inline float bfu2f(unsigned short u) {
    union { unsigned short u; __hip_bfloat16 b; } cv; cv.u = u;
    return __bfloat162float(cv.b);
}

// ---------------- fused prep kernel ----------------
// 32x32x16 frag order (k_heavy): lane&31 = row/col, k = ks*16 + (lane>>5)*8 + e.
// 16x16x32 frag order (k_fb): lane&15 = row/col, k = ks*32 + (lane>>4)*8 + e.
__global__ void k_prep(const float* __restrict__ Wd, const float* __restrict__ W0,
                       const float* __restrict__ A,
                       unsigned short* __restrict__ FB32,
                       unsigned short* __restrict__ FB16,
                       unsigned short* __restrict__ FBT16,
                       unsigned short* __restrict__ FW016,
                       unsigned short* __restrict__ FWT16,
                       unsigned short* __restrict__ FSA16,
                       float* __restrict__ FA,
                       float* __restrict__ ksq, float* __restrict__ trace) {
    int b = blockIdx.x, t = threadIdx.x;
    int lane = t & 63, l31 = lane & 31, lhi = lane >> 5;
    int l15 = lane & 15, lg4 = lane >> 4;
    if (b < 64) {
        int combo = b*4 + (t >> 6);
        int l = combo >> 7, rest = combo & 127;
        int mtile = rest >> 4, kstep = rest & 15;
        const float* src = Wd + l*65536 + (mtile*32 + l31)*256 + kstep*16 + lhi*8;
        int off = l*65536 + (mtile*16 + kstep)*512 + lane*8;
        #pragma unroll
        for (int e = 0; e < 8; ++e) FB32[off+e] = f2bfu(src[e]);
    } else if (b < 128) {
        int combo = (b-64)*4 + (t >> 6);
        int l = combo >> 7, rest = combo & 127;
        int mt = rest >> 3, ks = rest & 7;
        const float* src = Wd + l*65536 + (mt*16 + l15)*256 + ks*32 + lg4*8;
        int off = l*65536 + (mt*8 + ks)*512 + lane*8;
        #pragma unroll
        for (int e = 0; e < 8; ++e) FB16[off+e] = f2bfu(src[e]);
    } else if (b < 192) {
        int combo = (b-128)*4 + (t >> 6);
        int l = combo >> 7, rest = combo & 127;
        int kt = rest >> 3, ms = rest & 7;
        const float* src = Wd + l*65536 + (ms*32 + lg4*8)*256 + kt*16 + l15;
        int off = l*65536 + (kt*8 + ms)*512 + lane*8;
        #pragma unroll
        for (int e = 0; e < 8; ++e) FBT16[off+e] = f2bfu(src[e*256]);
    } else if (b < 200) {
        int combo = (b-192)*4 + (t >> 6);
        int mt = combo >> 1, ks = combo & 1;
        const float* src = W0 + (mt*16 + l15)*64 + ks*32 + lg4*8;
        int off = combo*512 + lane*8;
        #pragma unroll
        for (int e = 0; e < 8; ++e) FW016[off+e] = f2bfu(src[e]);
    } else if (b < 208) {
        int combo = (b-200)*4 + (t >> 6);
        int ct = combo >> 3, ms = combo & 7;
        const float* src = W0 + (ms*32 + lg4*8)*64 + ct*16 + l15;
        int off = combo*512 + lane*8;
        #pragma unroll
        for (int e = 0; e < 8; ++e) FWT16[off+e] = f2bfu(src[e*64]);
    } else if (b < 210) {
        int combo = (b-208)*4 + (t >> 6);
        int ct = combo >> 1, ks = combo & 1;
        int c = ct*16 + l15;
        int off = combo*512 + lane*8;
        #pragma unroll
        for (int e = 0; e < 8; ++e) {
            int j = ks*32 + lg4*8 + e;
            float s = 0.f;
            #pragma unroll
            for (int r = 0; r < 10; ++r) s += A[r*64+c] * A[r*64+j];
            FSA16[off+e] = f2bfu(s);
        }
    } else if (b == 210) {
        float s = 0.f;
        for (int dd = 0; dd < 63; dd++) { float v = W0[t*64+dd]; s += v*v; }
        ksq[t] = s;
        float p = 0.f;
        for (int idx = t; idx < 630; idx += 256) {
            int r = idx / 63, i = idx % 63;
            float v = A[r*64+i]; p += v*v;
        }
        for (int off = 32; off; off >>= 1) p += __shfl_down(p, off, 64);
        __shared__ float red[4];
        if ((t & 63) == 0) red[t >> 6] = p;
        __syncthreads();
        if (t == 0) trace[0] = red[0]+red[1]+red[2]+red[3];
    } else {
        int q = (b-211)*256 + t;            // [0,2048)
        int tl = q & 63, frag = q >> 6;     // frag = dh*16+ks in [0,32)
        int d  = (frag >> 4)*32 + (tl & 31);
        int m0 = (frag & 15)*16 + (tl >> 5)*8;
        float* dst = FA + q*8;
        #pragma unroll
        for (int e = 0; e < 8; ++e)
            dst[e] = (d == 63) ? 0.f : W0[(m0 + e)*64 + d];
    }
}

// ---------------- fused fwd+bwd MFMA kernel: 16 ex/block, 256 blocks, 512 thr ----------------
__global__ __launch_bounds__(512, 1) void k_fb(
        const float* __restrict__ x, const float* __restrict__ b0,
        const float* __restrict__ bd, const float* __restrict__ wv,
        const float* __restrict__ cw,
        const unsigned short* __restrict__ FW016,
        const unsigned short* __restrict__ FB16,
        const unsigned short* __restrict__ FBT16,
        const unsigned short* __restrict__ FWT16,
        const unsigned short* __restrict__ FSA16,
        float* __restrict__ tanhopen, float* __restrict__ tp0g,
        float* __restrict__ tp1g, float* __restrict__ z2T, float* __restrict__ z1T,
        float* __restrict__ out) {
    __shared__ __align__(16) unsigned short Buh[4096], Bul[4096];   // 8 ks x 512
    __shared__ __align__(16) unsigned short Bxh[1024], Bxl[1024];   // 2 ks x 512
    __shared__ __align__(16) float bounce[16*257];                  // also gpart[8*256]
    __shared__ float b0s[256], bd0s[256], bd1s[256], wvs[256], cws[64];
    int n0 = blockIdx.x * 16, t = threadIdx.x;
    int lane = t & 63, w = t >> 6, l15 = lane & 15, lg4 = lane >> 4;

    if (t < 256) { b0s[t]=b0[t]; bd0s[t]=bd[t]; bd1s[t]=bd[256+t]; wvs[t]=wv[t]; }
    if (t >= 256 && t < 320) cws[t-256] = cw[t-256];
    if (t < 128) {
        int tl = t & 63;
        int ex = tl & 15, k0 = (t >> 6)*32 + (tl >> 4)*8;
        const float* xp = x + (n0+ex)*64 + k0;
        short8 h8, l8;
        #pragma unroll
        for (int e = 0; e < 8; ++e) {
            float v = xp[e];
            unsigned short h = f2bfu(v);
            h8[e] = (short)h; l8[e] = (short)f2bfu(v - bfu2f(h));
        }
        *reinterpret_cast<short8*>(&Bxh[t*8]) = h8;
        *reinterpret_cast<short8*>(&Bxl[t*8]) = l8;
    }
    __syncthreads();

#define MROW(J, R) ((w*2+(J))*16 + lg4*4 + (R))

#define GEMM256_16(PH) do { \
    _Pragma("unroll") \
    for (int ks = 0; ks < 8; ++ks) { \
        short8 Bh = *reinterpret_cast<const short8*>(&Buh[(ks*64+lane)*8]); \
        short8 Bl = *reinterpret_cast<const short8*>(&Bul[(ks*64+lane)*8]); \
        _Pragma("unroll") \
        for (int j = 0; j < 2; ++j) { \
            short8 Aj = *reinterpret_cast<const short8*>(PH + ((w*2+j)*8 + ks)*512 + lane*8); \
            acc[j] = __builtin_amdgcn_mfma_f32_16x16x32_bf16(Aj, Bh, acc[j], 0, 0, 0); \
            acc[j] = __builtin_amdgcn_mfma_f32_16x16x32_bf16(Aj, Bl, acc[j], 0, 0, 0); \
        } \
    } \
} while (0)

#define EPILOGUE(SVAL, DST, BVAL) do { \
    __syncthreads(); \
    _Pragma("unroll") \
    for (int v = 0; v < 8; ++v) bounce[l15*257 + MROW(v>>2, v&3)] = SVAL[v]; \
    _Pragma("unroll") \
    for (int j = 0; j < 2; ++j) { \
        int m0_ = (w*2+j)*16 + lg4*4; \
        int base_ = (((m0_>>5)*64) + ((m0_>>3)&3)*16 + l15)*8 + (m0_&7); \
        ushort4v h4, l4; \
        _Pragma("unroll") \
        for (int q = 0; q < 4; ++q) { \
            float v_ = BVAL[j*4+q]; \
            unsigned short h_ = f2bfu(v_); \
            h4[q] = h_; l4[q] = f2bfu(v_ - bfu2f(h_)); \
        } \
        *reinterpret_cast<ushort4v*>(&Buh[base_]) = h4; \
        *reinterpret_cast<ushort4v*>(&Bul[base_]) = l4; \
    } \
    __syncthreads(); \
    _Pragma("unroll") \
    for (int i = 0; i < 8; ++i) { \
        int f = t + i*512; int ex_ = f >> 8, m_ = f & 255; \
        DST[(n0+ex_)*256 + m_] = bounce[ex_*257 + m_]; \
    } \
} while (0)

    floatx4 acc[2];
    float sv[8], u0v[8], tp0v[8], z2v[8], cf[8];

    // ---- opening (K=64, A=FW016, B=Bx) ----
    #pragma unroll
    for (int j = 0; j < 2; ++j) acc[j] = (floatx4){0.f,0.f,0.f,0.f};
    #pragma unroll
    for (int ks = 0; ks < 2; ++ks) {
        short8 Bh = *reinterpret_cast<const short8*>(&Bxh[(ks*64+lane)*8]);
        short8 Bl = *reinterpret_cast<const short8*>(&Bxl[(ks*64+lane)*8]);
        #pragma unroll
        for (int j = 0; j < 2; ++j) {
            short8 Aj = *reinterpret_cast<const short8*>(FW016 + ((w*2+j)*2 + ks)*512 + lane*8);
            acc[j] = __builtin_amdgcn_mfma_f32_16x16x32_bf16(Aj, Bh, acc[j], 0, 0, 0);
            acc[j] = __builtin_amdgcn_mfma_f32_16x16x32_bf16(Aj, Bl, acc[j], 0, 0, 0);
        }
    }
    #pragma unroll
    for (int v = 0; v < 8; ++v) {
        float p = acc[v>>2][v&3] + b0s[MROW(v>>2, v&3)];
        float a = fabsf(p);
        float e = __expf(-2.f*a);
        float th = (1.f - e) * __builtin_amdgcn_rcpf(1.f + e);
        sv[v] = __builtin_copysignf(th, p);
        u0v[v] = a + __logf(1.f + e);
    }
    EPILOGUE(sv, tanhopen, u0v);

    // ---- pre0 (A=FB16 layer0, B=u0) ----
    #pragma unroll
    for (int j = 0; j < 2; ++j) acc[j] = (floatx4){0.f,0.f,0.f,0.f};
    GEMM256_16(FB16);
    #pragma unroll
    for (int v = 0; v < 8; ++v) {
        float p = acc[v>>2][v&3] + bd0s[MROW(v>>2, v&3)];
        float a = fabsf(p);
        float e = __expf(-2.f*a);
        float th = (1.f - e) * __builtin_amdgcn_rcpf(1.f + e);
        tp0v[v] = __builtin_copysignf(th, p);
        u0v[v] += 0.5f*(a + __logf(1.f + e));   // now u1
    }
    EPILOGUE(tp0v, tp0g, u0v);

    // ---- pre1 (A=FB16 layer1, B=u1) ----
    #pragma unroll
    for (int j = 0; j < 2; ++j) acc[j] = (floatx4){0.f,0.f,0.f,0.f};
    GEMM256_16(FB16 + 65536);
    #pragma unroll
    for (int v = 0; v < 8; ++v) {
        float p = acc[v>>2][v&3] + bd1s[MROW(v>>2, v&3)];
        float a = fabsf(p);
        float e = __expf(-2.f*a);
        float th = (1.f - e) * __builtin_amdgcn_rcpf(1.f + e);
        cf[v] = __builtin_copysignf(th, p);
        z2v[v] = cf[v] * wvs[MROW(v>>2, v&3)];   // coef2 = tp1*wv
    }
    EPILOGUE(cf, tp1g, z2v);

    // ---- z2 (A=FBT16 layer1, B=coef2) ----
    #pragma unroll
    for (int j = 0; j < 2; ++j) acc[j] = (floatx4){0.f,0.f,0.f,0.f};
    GEMM256_16(FBT16 + 65536);
    #pragma unroll
    for (int v = 0; v < 8; ++v) {
        z2v[v] = wvs[MROW(v>>2, v&3)] + 0.5f*acc[v>>2][v&3];
        cf[v] = tp0v[v] * z2v[v];                // coef1
    }
    EPILOGUE(z2v, z2T, cf);

    // ---- z1 (A=FBT16 layer0, B=coef1) ----
    #pragma unroll
    for (int j = 0; j < 2; ++j) acc[j] = (floatx4){0.f,0.f,0.f,0.f};
    GEMM256_16(FBT16);
    #pragma unroll
    for (int v = 0; v < 8; ++v) {
        z2v[v] += 0.5f*acc[v>>2][v&3];           // now z1
        cf[v] = sv[v] * z2v[v];                  // coef0
    }
    EPILOGUE(z2v, z1T, cf);

    // ---- grad: c-tile ct = w&3, K-seg = w>>2; A=FWT16 (coef0) + FSA16 (x, seg1) ----
    {
        int ct = w & 3, seg = w >> 2;
        floatx4 ga = (floatx4){0.f,0.f,0.f,0.f};
        #pragma unroll
        for (int k2 = 0; k2 < 4; ++k2) {
            int ms = seg*4 + k2;
            short8 Bh = *reinterpret_cast<const short8*>(&Buh[(ms*64+lane)*8]);
            short8 Bl = *reinterpret_cast<const short8*>(&Bul[(ms*64+lane)*8]);
            short8 Aj = *reinterpret_cast<const short8*>(FWT16 + (ct*8 + ms)*512 + lane*8);
            ga = __builtin_amdgcn_mfma_f32_16x16x32_bf16(Aj, Bh, ga, 0, 0, 0);
            ga = __builtin_amdgcn_mfma_f32_16x16x32_bf16(Aj, Bl, ga, 0, 0, 0);
        }
        if (seg == 1) {
            #pragma unroll
            for (int ks = 0; ks < 2; ++ks) {
                short8 Bh = *reinterpret_cast<const short8*>(&Bxh[(ks*64+lane)*8]);
                short8 Bl = *reinterpret_cast<const short8*>(&Bxl[(ks*64+lane)*8]);
                short8 Aj = *reinterpret_cast<const short8*>(FSA16 + (ct*2 + ks)*512 + lane*8);
                ga = __builtin_amdgcn_mfma_f32_16x16x32_bf16(Aj, Bh, ga, 0, 0, 0);
                ga = __builtin_amdgcn_mfma_f32_16x16x32_bf16(Aj, Bl, ga, 0, 0, 0);
            }
        }
        __syncthreads();   // bounce free (z1 stores done)
        float* gpart = bounce;   // [8 w][16 row][16 ex]
        #pragma unroll
        for (int r = 0; r < 4; ++r) gpart[w*256 + (lg4*4 + r)*16 + l15] = ga[r];
        __syncthreads();
        if (t < 256) {
            int o0 = t*4, ex = o0 >> 6, c0 = o0 & 63;
            float4 gv;
            #pragma unroll
            for (int jj = 0; jj < 4; ++jj) {
                int c = c0 + jj;
                int ct2 = c >> 4, cr = c & 15;
                gv[jj] = cws[c] + gpart[ct2*256 + cr*16 + ex]
                                + gpart[(ct2+4)*256 + cr*16 + ex];
            }
            *reinterpret_cast<float4*>(&out[(n0+ex)*64 + c0]) = gv;
        }
    }
#undef MROW
#undef GEMM256_16
#undef EPILOGUE
}

// ---------------- heavy Jacobian kernel: round-18 proven best (78.4 us) ----------------
// 256 thr, 1 ex/block, (256,3); __syncthreads barriers; 4-deep A / 2-deep B pipeline;
// no setprio. 76 VGPR arch + 64 AGPR, 3 blocks/CU, WRITE_SIZE 128 B.
__global__ __launch_bounds__(256, 3) void k_heavy_mfma(
        const float* __restrict__ tanhopen, const float* __restrict__ tp0,
        const float* __restrict__ tp1, const float* __restrict__ z2T,
        const float* __restrict__ z1T, const float* __restrict__ wv,
        const float* __restrict__ FA, const unsigned short* __restrict__ FB,
        const float* __restrict__ ksq, const float* __restrict__ trace,
        float* __restrict__ outTrH) {
    __shared__ __align__(16) unsigned short Bf[16384];   // 32 KB: 32 frags x 512
    __shared__ float ss[256], tp0s[256], w1s[256], w2s[256];
    __shared__ float red[4];
    int n = blockIdx.x, t = threadIdx.x;           // t in [0,256)
    int lane = t & 63, w = t >> 6, l31 = lane & 31, lhi = lane >> 5;

    float sv = tanhopen[n*256 + t];
    float a0 = tp0[n*256 + t];
    float a1 = tp1[n*256 + t];
    ss[t] = sv;
    tp0s[t] = a0;
    w1s[t] = (1.f - a0*a0) * z2T[n*256 + t];
    w2s[t] = (1.f - a1*a1) * wv[t];
    float tot = (1.f - sv*sv) * z1T[n*256 + t] * ksq[t];   // trH layer-0 partial (m=t)
    __syncthreads();

    // build Bf[frag= dh*16+ks][tl][e] = bf16( W0T[d][k] * ss[k] )
    #pragma unroll
    for (int i = 0; i < 8; ++i) {
        int q = t + i*256;                  // [0,2048) lane-chunks of short8
        int frag = q >> 6, tl = q & 63;
        int k0 = (frag & 15)*16 + (tl >> 5)*8;
        const float* fp = FA + q*8;         // FA layout matches frag*64+tl
        short8 v8;
        #pragma unroll
        for (int e = 0; e < 8; ++e)
            v8[e] = (short)f2bfu(fp[e] * ss[k0 + e]);
        *reinterpret_cast<short8*>(&Bf[q*8]) = v8;
    }
    __syncthreads();

    floatx16 acc[2][2];   // [m-tile jm][d-half dh]
    int mt0 = w*2, mt1 = w*2 + 1;
    float wtot = 0.f;

    const unsigned short* pA0 = FB + mt0*16*512 + lane*8;   // layer 0, ks stride 512
    const unsigned short* pA1 = FB + mt1*16*512 + lane*8;
    const unsigned short* qB0 = &Bf[lane*8];                // dh=0, ks stride 512
    const unsigned short* qB1 = &Bf[(16*64 + lane)*8];      // dh=1

#define LD8(P, KS) (*reinterpret_cast<const short8*>((P) + (KS)*512))
#define MFMA4(A0_, A1_, B0_, B1_) do { \
    acc[0][0] = __builtin_amdgcn_mfma_f32_32x32x16_bf16(A0_, B0_, acc[0][0], 0, 0, 0); \
    acc[0][1] = __builtin_amdgcn_mfma_f32_32x32x16_bf16(A0_, B1_, acc[0][1], 0, 0, 0); \
    acc[1][0] = __builtin_amdgcn_mfma_f32_32x32x16_bf16(A1_, B0_, acc[1][0], 0, 0, 0); \
    acc[1][1] = __builtin_amdgcn_mfma_f32_32x32x16_bf16(A1_, B1_, acc[1][1], 0, 0, 0); \
} while (0)

    // ---------------- layer 0: KJ1 = Wd0 @ Jac (4-deep A, 2-deep B) ----------------
    #pragma unroll
    for (int jm = 0; jm < 2; ++jm)
        #pragma unroll
        for (int dh = 0; dh < 2; ++dh)
            #pragma unroll
            for (int r = 0; r < 16; ++r) acc[jm][dh][r] = 0.f;

    {
        short8 A0s[4], A1s[4], B0s[2], B1s[2];
        A0s[0] = LD8(pA0, 0); A1s[0] = LD8(pA1, 0);
        A0s[1] = LD8(pA0, 1); A1s[1] = LD8(pA1, 1);
        A0s[2] = LD8(pA0, 2); A1s[2] = LD8(pA1, 2);
        B0s[0] = LD8(qB0, 0); B1s[0] = LD8(qB1, 0);
        #pragma unroll
        for (int ks = 0; ks < 16; ++ks) {
            if (ks + 3 < 16) {
                A0s[(ks+3)&3] = LD8(pA0, ks+3);
                A1s[(ks+3)&3] = LD8(pA1, ks+3);
            }
            if (ks + 1 < 16) {
                B0s[(ks+1)&1] = LD8(qB0, ks+1);
                B1s[(ks+1)&1] = LD8(qB1, ks+1);
            }
            MFMA4(A0s[ks&3], A1s[ks&3], B0s[ks&1], B1s[ks&1]);
        }
    }

    // prefetch layer-1 first A stages (global; independent of the RMW below)
    const unsigned short* pC0 = FB + 65536 + mt0*16*512 + lane*8;
    const unsigned short* pC1 = FB + 65536 + mt1*16*512 + lane*8;
    short8 nA00 = LD8(pC0, 0), nA10 = LD8(pC1, 0);
    short8 nA01 = LD8(pC0, 1), nA11 = LD8(pC1, 1);
    short8 nA02 = LD8(pC0, 2), nA12 = LD8(pC1, 2);

    __syncthreads();   // all layer-0 B-reads done before update writes

    // trH layer-1 + Jac update: Jac[m][d] += 0.5*tp0[m]*KJ1[m][d]
    #pragma unroll
    for (int jm = 0; jm < 2; ++jm) {
        int mt = w*2 + jm;
        #pragma unroll
        for (int g = 0; g < 4; ++g) {
            float w1m[4], tm[4];
            #pragma unroll
            for (int q = 0; q < 4; ++q) {
                int m = mt*32 + 8*g + q + 4*lhi;
                w1m[q] = 0.5f * w1s[m];
                tm[q]  = 0.5f * tp0s[m];
            }
            #pragma unroll
            for (int dh = 0; dh < 2; ++dh) {
                int base = ((dh*16 + mt*2 + (g >> 1))*64
                            + ((g & 1)*32 + l31))*8 + 4*lhi;
                ushort4v old = *reinterpret_cast<ushort4v*>(&Bf[base]);
                ushort4v nw;
                #pragma unroll
                for (int q = 0; q < 4; ++q) {
                    float v = acc[jm][dh][4*g + q];
                    wtot += w1m[q] * v * v;
                    nw[q] = f2bfu(bfu2f(old[q]) + tm[q] * v);
                }
                *reinterpret_cast<ushort4v*>(&Bf[base]) = nw;
            }
        }
    }
    __syncthreads();   // updates visible before layer-1 reads

    // ---------------- layer 1: KJ2 = Wd1 @ Jac_new (4-deep A, 2-deep B) ----------------
    #pragma unroll
    for (int jm = 0; jm < 2; ++jm)
        #pragma unroll
        for (int dh = 0; dh < 2; ++dh)
            #pragma unroll
            for (int r = 0; r < 16; ++r) acc[jm][dh][r] = 0.f;

    {
        short8 A0s[4], A1s[4], B0s[2], B1s[2];
        A0s[0] = nA00; A1s[0] = nA10;
        A0s[1] = nA01; A1s[1] = nA11;
        A0s[2] = nA02; A1s[2] = nA12;
        B0s[0] = LD8(qB0, 0); B1s[0] = LD8(qB1, 0);
        #pragma unroll
        for (int ks = 0; ks < 16; ++ks) {
            if (ks + 3 < 16) {
                A0s[(ks+3)&3] = LD8(pC0, ks+3);
                A1s[(ks+3)&3] = LD8(pC1, ks+3);
            }
            if (ks + 1 < 16) {
                B0s[(ks+1)&1] = LD8(qB0, ks+1);
                B1s[(ks+1)&1] = LD8(qB1, ks+1);
            }
            MFMA4(A0s[ks&3], A1s[ks&3], B0s[ks&1], B1s[ks&1]);
        }
    }
#undef MFMA4
#undef LD8

    // trH layer-2 term
    #pragma unroll
    for (int jm = 0; jm < 2; ++jm)
        #pragma unroll
        for (int g = 0; g < 4; ++g)
            #pragma unroll
            for (int q = 0; q < 4; ++q) {
                int m = (w*2 + jm)*32 + 8*g + q + 4*lhi;
                float w2m = 0.5f * w2s[m];
                float v0 = acc[jm][0][4*g + q], v1 = acc[jm][1][4*g + q];
                wtot += w2m * (v0*v0 + v1*v1);
            }

    tot += wtot;

    // reduce 256 -> 1
    for (int off = 32; off; off >>= 1) tot += __shfl_down(tot, off, 64);
    if (lane == 0) red[w] = tot;
    __syncthreads();
    if (t == 0) outTrH[n] = red[0] + red[1] + red[2] + red[3] + trace[0];
}

// ---------------- launcher ----------------

extern "C" void kernel_launch(void* const* d_in, const int* in_sizes, int n_in,
                              void* d_out, int out_size, void* d_ws, size_t ws_size,
                              hipStream_t stream) {
    const float* x   = (const float*)d_in[0];   // 4096*64
    const float* W0  = (const float*)d_in[1];   // 256*64
    const float* b0  = (const float*)d_in[2];   // 256
    const float* Wd  = (const float*)d_in[3];   // 2*256*256
    const float* bd  = (const float*)d_in[4];   // 2*256
    const float* wv  = (const float*)d_in[5];   // 256
    const float* A   = (const float*)d_in[6];   // 10*64
    const float* cw  = (const float*)d_in[7];   // 64
    float* out = (float*)d_out;
    float* ws  = (float*)d_ws;

    float* tanhopen = ws;               // NM
    float* tp0  = tanhopen + NM;        // NM
    float* tp1  = tp0 + NM;             // NM
    float* z2T  = tp1 + NM;             // NM
    float* z1T  = z2T + NM;             // NM
    float* FA   = z1T + NM;             // 16384
    float* ksq  = FA + 16384;           // 256
    float* trace= ksq + 256;            // 4 (padded for alignment)
    unsigned short* FB32  = (unsigned short*)(trace + 4); // 131072
    unsigned short* FB16  = FB32 + 131072;                // 131072
    unsigned short* FBT16 = FB16 + 131072;                // 131072
    unsigned short* FW016 = FBT16 + 131072;               // 16384
    unsigned short* FWT16 = FW016 + 16384;                // 16384
    unsigned short* FSA16 = FWT16 + 16384;                // 4096

    k_prep<<<219, 256, 0, stream>>>(Wd, W0, A, FB32, FB16, FBT16,
                                    FW016, FWT16, FSA16, FA, ksq, trace);
    k_fb<<<NEX/16, 512, 0, stream>>>(x, b0, bd, wv, cw,
                                     FW016, FB16, FBT16, FWT16, FSA16,
                                     tanhopen, tp0, tp1, z2T, z1T, out);
    k_heavy_mfma<<<NEX, 256, 0, stream>>>(tanhopen, tp0, tp1, z2T, z1T, wv,
                                          FA, FB32, ksq, trace, out + NEX*64);
}